// Round 2
// baseline (903.543 us; speedup 1.0000x reference)
//
#include <hip/hip_runtime.h>
#include <hip/hip_bf16.h>
#include <stdint.h>

#define N_NODES 50000
#define N_EDGES 800000

// ---------------------------------------------------------------- degree count
__global__ __launch_bounds__(256) void count_deg_kernel(
    const int* __restrict__ dst, unsigned* __restrict__ cnt, int nE)
{
    int i = blockIdx.x * blockDim.x + threadIdx.x;
    if (i < nE) {
        unsigned d = (unsigned)dst[i];
        if (d < N_NODES) atomicAdd(&cnt[d], 1u);
    }
}

// ---------------------------------------------------------------- dinv = rsqrt(deg+1)
__global__ __launch_bounds__(256) void dinv_kernel(
    const unsigned* __restrict__ cnt, float* __restrict__ dinv, int n)
{
    int i = blockIdx.x * blockDim.x + threadIdx.x;
    if (i < n) dinv[i] = rsqrtf((float)(cnt[i] + 1u));
}

// ---------------------------------------------------------------- exclusive scan (single block)
__global__ __launch_bounds__(1024) void scan_kernel(
    const unsigned* __restrict__ cnt, unsigned* __restrict__ off, int n)
{
    __shared__ unsigned tmp[1024];
    int t = threadIdx.x;
    unsigned carry = 0;
    for (int base = 0; base < n; base += 1024) {
        int i = base + t;
        unsigned v = (i < n) ? cnt[i] : 0u;
        tmp[t] = v;
        __syncthreads();
        for (int s = 1; s < 1024; s <<= 1) {
            unsigned add = (t >= s) ? tmp[t - s] : 0u;
            __syncthreads();
            tmp[t] += add;
            __syncthreads();
        }
        if (i < n) off[i] = carry + tmp[t] - v;
        carry += tmp[1023];
        __syncthreads();   // protect tmp before next iteration overwrites
    }
    if (t == 0) off[n] = carry;
}

// ---------------------------------------------------------------- CSR fill (counting sort by dst)
__global__ __launch_bounds__(256) void fill_csr_kernel(
    const int* __restrict__ src, const int* __restrict__ dst,
    const unsigned* __restrict__ off, unsigned* __restrict__ cursor,
    int* __restrict__ csr_src, int nE)
{
    int i = blockIdx.x * blockDim.x + threadIdx.x;
    if (i < nE) {
        unsigned d = (unsigned)dst[i];
        unsigned s = (unsigned)src[i];
        if (d < N_NODES && s < N_NODES) {
            unsigned slot = off[d] + atomicAdd(&cursor[d], 1u);
            csr_src[slot] = (int)s;
        }
    }
}

// ---------------------------------------------------------------- fp32 tiled GEMM, epilogue Y = dinv[row] * (A@W)
// A: M x K (row stride lda), W: K x N row-major, Y: M x N
#define BM 64
#define BN 64
#define BK 16
__global__ __launch_bounds__(256) void gemm_dinv_kernel(
    const float* __restrict__ A, int lda,
    const float* __restrict__ W,
    const float* __restrict__ dinv,
    float* __restrict__ Y,
    int M, int K, int N)
{
    __shared__ float As[BK][BM];   // A^T tile
    __shared__ float Bs[BK][BN];

    const int t  = threadIdx.x;
    const int bm = blockIdx.x * BM;
    const int bn = blockIdx.y * BN;

    const int arow = t >> 2;            // 0..63
    const int akq  = (t & 3) * 4;       // 0,4,8,12
    const int brow = t >> 4;            // 0..15
    const int bnq  = (t & 15) * 4;      // 0..60

    const int tm = (t >> 4) * 4;        // 0..60
    const int tn = (t & 15) * 4;        // 0..60

    float acc[4][4] = {};

    for (int k0 = 0; k0 < K; k0 += BK) {
        // load A tile (with M guard)
        float4 av;
        int gr = bm + arow;
        if (gr < M) {
            av = *(const float4*)(A + (size_t)gr * lda + k0 + akq);
        } else {
            av = make_float4(0.f, 0.f, 0.f, 0.f);
        }
        As[akq + 0][arow] = av.x;
        As[akq + 1][arow] = av.y;
        As[akq + 2][arow] = av.z;
        As[akq + 3][arow] = av.w;
        // load B tile
        float4 bv = *(const float4*)(W + (size_t)(k0 + brow) * N + bn + bnq);
        *(float4*)&Bs[brow][bnq] = bv;
        __syncthreads();

        #pragma unroll
        for (int kk = 0; kk < BK; ++kk) {
            float4 a = *(const float4*)&As[kk][tm];
            float4 b = *(const float4*)&Bs[kk][tn];
            acc[0][0] = fmaf(a.x, b.x, acc[0][0]);
            acc[0][1] = fmaf(a.x, b.y, acc[0][1]);
            acc[0][2] = fmaf(a.x, b.z, acc[0][2]);
            acc[0][3] = fmaf(a.x, b.w, acc[0][3]);
            acc[1][0] = fmaf(a.y, b.x, acc[1][0]);
            acc[1][1] = fmaf(a.y, b.y, acc[1][1]);
            acc[1][2] = fmaf(a.y, b.z, acc[1][2]);
            acc[1][3] = fmaf(a.y, b.w, acc[1][3]);
            acc[2][0] = fmaf(a.z, b.x, acc[2][0]);
            acc[2][1] = fmaf(a.z, b.y, acc[2][1]);
            acc[2][2] = fmaf(a.z, b.z, acc[2][2]);
            acc[2][3] = fmaf(a.z, b.w, acc[2][3]);
            acc[3][0] = fmaf(a.w, b.x, acc[3][0]);
            acc[3][1] = fmaf(a.w, b.y, acc[3][1]);
            acc[3][2] = fmaf(a.w, b.z, acc[3][2]);
            acc[3][3] = fmaf(a.w, b.w, acc[3][3]);
        }
        __syncthreads();
    }

    #pragma unroll
    for (int i = 0; i < 4; ++i) {
        int gr = bm + tm + i;
        if (gr < M) {
            float s = dinv[gr];
            float4 v = make_float4(acc[i][0] * s, acc[i][1] * s,
                                   acc[i][2] * s, acc[i][3] * s);
            *(float4*)(Y + (size_t)gr * N + bn + tn) = v;
        }
    }
}

// ---------------------------------------------------------------- aggregation
// out[v,f] = dinv[v] * ( y[v,f] + sum_{u in in(v)} y[u,f] ) + bias[f]   (+optional relu)
template<int F, bool RELU>
__global__ __launch_bounds__(F) void aggregate_kernel(
    const float* __restrict__ Y, const int* __restrict__ csr_src,
    const unsigned* __restrict__ off, const float* __restrict__ dinv,
    const float* __restrict__ bias, float* __restrict__ out)
{
    const int v = blockIdx.x;
    const int f = threadIdx.x;
    const unsigned e0 = off[v], e1 = off[v + 1];
    float acc = Y[(size_t)v * F + f];          // self-loop term (y already has dinv[src])
    for (unsigned j = e0; j < e1; ++j) {
        int u = csr_src[j];
        acc += Y[(size_t)u * F + f];
    }
    float r = acc * dinv[v] + bias[f];
    if (RELU) r = fmaxf(r, 0.f);
    out[(size_t)v * F + f] = r;
}

// ---------------------------------------------------------------- launch
extern "C" void kernel_launch(void* const* d_in, const int* in_sizes, int n_in,
                              void* d_out, int out_size, void* d_ws, size_t ws_size,
                              hipStream_t stream)
{
    const float* x  = (const float*)d_in[0];      // 50000 x 1100
    const int*   ei = (const int*)d_in[1];        // 2 x 800000 (int32 per harness contract)
    const float* W1 = (const float*)d_in[2];      // 512 x 256
    const float* b1 = (const float*)d_in[3];      // 256
    const float* W2 = (const float*)d_in[4];      // 256 x 128
    const float* b2 = (const float*)d_in[5];      // 128
    float*       out = (float*)d_out;             // 50000 x 128

    const int* e_src = ei;
    const int* e_dst = ei + N_EDGES;

    // workspace carve-up (512B aligned)
    char* ws = (char*)d_ws;
    size_t o = 0;
    auto carve = [&](size_t bytes) -> char* {
        char* p = ws + o;
        o = (o + bytes + 511) & ~(size_t)511;
        return p;
    };
    unsigned* cnt    = (unsigned*)carve((size_t)N_NODES * 4);
    unsigned* cursor = (unsigned*)carve((size_t)N_NODES * 4);
    unsigned* off    = (unsigned*)carve((size_t)(N_NODES + 1) * 4);
    float*    dinv   = (float*)   carve((size_t)N_NODES * 4);
    int*      csr    = (int*)     carve((size_t)N_EDGES * 4);
    float*    y1     = (float*)   carve((size_t)N_NODES * 256 * 4);  // reused as y2
    float*    h      = (float*)   carve((size_t)N_NODES * 256 * 4);
    (void)ws_size;

    hipMemsetAsync(cnt,    0, (size_t)N_NODES * 4, stream);
    hipMemsetAsync(cursor, 0, (size_t)N_NODES * 4, stream);

    // degree count + dinv + CSR
    count_deg_kernel<<<(N_EDGES + 255) / 256, 256, 0, stream>>>(e_dst, cnt, N_EDGES);
    dinv_kernel<<<(N_NODES + 255) / 256, 256, 0, stream>>>(cnt, dinv, N_NODES);
    scan_kernel<<<1, 1024, 0, stream>>>(cnt, off, N_NODES);
    fill_csr_kernel<<<(N_EDGES + 255) / 256, 256, 0, stream>>>(e_src, e_dst, off, cursor, csr, N_EDGES);

    // layer 1: y1 = dinv * (x[:,588:] @ W1)
    {
        dim3 grid((N_NODES + BM - 1) / BM, 256 / BN);
        gemm_dinv_kernel<<<grid, 256, 0, stream>>>(x + 588, 1100, W1, dinv, y1,
                                                   N_NODES, 512, 256);
    }
    // h = relu(dinv * rowsum(y1) + b1)
    aggregate_kernel<256, true><<<N_NODES, 256, 0, stream>>>(y1, csr, off, dinv, b1, h);

    // layer 2: y2 = dinv * (h @ W2)   (reuse y1 buffer)
    {
        dim3 grid((N_NODES + BM - 1) / BM, 128 / BN);
        gemm_dinv_kernel<<<grid, 256, 0, stream>>>(h, 256, W2, dinv, y1,
                                                   N_NODES, 256, 128);
    }
    // out = dinv * rowsum(y2) + b2
    aggregate_kernel<128, false><<<N_NODES, 128, 0, stream>>>(y1, csr, off, dinv, b2, out);
}

// Round 3
// 760.564 us; speedup vs baseline: 1.1880x; 1.1880x over previous
//
#include <hip/hip_runtime.h>
#include <hip/hip_bf16.h>
#include <stdint.h>

#define N_NODES 50000
#define N_EDGES 800000

// ---------------------------------------------------------------- degree count
__global__ __launch_bounds__(256) void count_deg_kernel(
    const int* __restrict__ dst, unsigned* __restrict__ cnt, int nE)
{
    int i = blockIdx.x * blockDim.x + threadIdx.x;
    if (i < nE) {
        unsigned d = (unsigned)dst[i];
        if (d < N_NODES) atomicAdd(&cnt[d], 1u);
    }
}

// ---------------------------------------------------------------- dinv = rsqrt(deg+1)
__global__ __launch_bounds__(256) void dinv_kernel(
    const unsigned* __restrict__ cnt, float* __restrict__ dinv, int n)
{
    int i = blockIdx.x * blockDim.x + threadIdx.x;
    if (i < n) dinv[i] = rsqrtf((float)(cnt[i] + 1u));
}

// ---------------------------------------------------------------- hierarchical scan
// stage 1: per-block (1024-elem chunk) reduction
__global__ __launch_bounds__(256) void block_reduce_kernel(
    const unsigned* __restrict__ cnt, unsigned* __restrict__ blockSums, int n)
{
    __shared__ unsigned s[256];
    int b = blockIdx.x;
    int base = b * 1024;
    unsigned v = 0;
    for (int i = threadIdx.x; i < 1024; i += 256) {
        int idx = base + i;
        v += (idx < n) ? cnt[idx] : 0u;
    }
    s[threadIdx.x] = v; __syncthreads();
    for (int st = 128; st > 0; st >>= 1) {
        if (threadIdx.x < st) s[threadIdx.x] += s[threadIdx.x + st];
        __syncthreads();
    }
    if (threadIdx.x == 0) blockSums[b] = s[0];
}

// stage 2: single block exclusive-scan of block sums (nb <= 64), writes off[n]=total
__global__ __launch_bounds__(64) void scan_sums_kernel(
    unsigned* __restrict__ blockSums, unsigned* __restrict__ off, int nb, int n)
{
    __shared__ unsigned s[64];
    int t = threadIdx.x;
    unsigned v = (t < nb) ? blockSums[t] : 0u;
    s[t] = v; __syncthreads();
    for (int st = 1; st < 64; st <<= 1) {
        unsigned add = (t >= st) ? s[t - st] : 0u;
        __syncthreads();
        s[t] += add;
        __syncthreads();
    }
    if (t < nb) blockSums[t] = s[t] - v;   // exclusive
    if (t == 0) off[n] = s[63];            // grand total
}

// stage 3: per-block exclusive scan of 1024-elem chunk + block offset
__global__ __launch_bounds__(1024) void block_scan_kernel(
    const unsigned* __restrict__ cnt, const unsigned* __restrict__ blockSums,
    unsigned* __restrict__ off, int n)
{
    __shared__ unsigned s[1024];
    int b = blockIdx.x, t = threadIdx.x;
    int i = b * 1024 + t;
    unsigned v = (i < n) ? cnt[i] : 0u;
    s[t] = v; __syncthreads();
    for (int st = 1; st < 1024; st <<= 1) {
        unsigned add = (t >= st) ? s[t - st] : 0u;
        __syncthreads();
        s[t] += add;
        __syncthreads();
    }
    if (i < n) off[i] = blockSums[b] + s[t] - v;
}

// ---------------------------------------------------------------- CSR fill (counting sort by dst)
__global__ __launch_bounds__(256) void fill_csr_kernel(
    const int* __restrict__ src, const int* __restrict__ dst,
    const unsigned* __restrict__ off, unsigned* __restrict__ cursor,
    int* __restrict__ csr_src, int nE)
{
    int i = blockIdx.x * blockDim.x + threadIdx.x;
    if (i < nE) {
        unsigned d = (unsigned)dst[i];
        unsigned s = (unsigned)src[i];
        if (d < N_NODES && s < N_NODES) {
            unsigned slot = off[d] + atomicAdd(&cursor[d], 1u);
            csr_src[slot] = (int)s;
        }
    }
}

// ---------------------------------------------------------------- fp32 tiled GEMM, 128x128 tile, 8x8/thread
// Y = dinv[row] * (A @ W);  A: M x K (row stride lda), W: K x N row-major
#define BM 128
#define BN 128
#define BK 16
__global__ __launch_bounds__(256, 2) void gemm_dinv_kernel(
    const float* __restrict__ A, int lda,
    const float* __restrict__ W,
    const float* __restrict__ dinv,
    float* __restrict__ Y,
    int M, int K, int N)
{
    __shared__ float As[BK][BM + 4];   // A^T tile, padded (132 % 4 == 0 keeps 16B align)
    __shared__ float Bs[BK][BN];

    const int t  = threadIdx.x;
    const int bm = blockIdx.x * BM;
    const int bn = blockIdx.y * BN;

    // staging indices
    const int ar  = t >> 2;            // 0..63 (+64 second half)
    const int akq = (t & 3) * 4;       // k offset 0,4,8,12
    const int br  = t >> 5;            // 0..7 (+8 second half)
    const int bnq = (t & 31) * 4;      // 0..124

    const int tx = t & 15;
    const int ty = t >> 4;
    const int tm = ty * 4;             // rows tm..tm+3 and tm+64..tm+67
    const int tn = tx * 4;             // cols tn..tn+3 and tn+64..tn+67

    float acc[8][8] = {};

    for (int k0 = 0; k0 < K; k0 += BK) {
        #pragma unroll
        for (int h = 0; h < 2; ++h) {
            int r  = ar + h * 64;
            int gr = bm + r;
            float4 av = (gr < M) ? *(const float4*)(A + (size_t)gr * lda + k0 + akq)
                                 : make_float4(0.f, 0.f, 0.f, 0.f);
            As[akq + 0][r] = av.x; As[akq + 1][r] = av.y;
            As[akq + 2][r] = av.z; As[akq + 3][r] = av.w;
        }
        #pragma unroll
        for (int h = 0; h < 2; ++h) {
            int kr = br + h * 8;
            *(float4*)&Bs[kr][bnq] = *(const float4*)(W + (size_t)(k0 + kr) * N + bn + bnq);
        }
        __syncthreads();

        #pragma unroll
        for (int kk = 0; kk < BK; ++kk) {
            float4 a0 = *(const float4*)&As[kk][tm];
            float4 a1 = *(const float4*)&As[kk][tm + 64];
            float4 b0 = *(const float4*)&Bs[kk][tn];
            float4 b1 = *(const float4*)&Bs[kk][tn + 64];
            float a[8] = {a0.x, a0.y, a0.z, a0.w, a1.x, a1.y, a1.z, a1.w};
            float b[8] = {b0.x, b0.y, b0.z, b0.w, b1.x, b1.y, b1.z, b1.w};
            #pragma unroll
            for (int i = 0; i < 8; ++i)
                #pragma unroll
                for (int j = 0; j < 8; ++j)
                    acc[i][j] = fmaf(a[i], b[j], acc[i][j]);
        }
        __syncthreads();
    }

    #pragma unroll
    for (int i = 0; i < 8; ++i) {
        int r  = (i < 4) ? (tm + i) : (tm + 64 + (i - 4));
        int gr = bm + r;
        if (gr < M) {
            float s = dinv[gr];
            float4 v0 = make_float4(acc[i][0] * s, acc[i][1] * s, acc[i][2] * s, acc[i][3] * s);
            float4 v1 = make_float4(acc[i][4] * s, acc[i][5] * s, acc[i][6] * s, acc[i][7] * s);
            *(float4*)(Y + (size_t)gr * N + bn + tn)      = v0;
            *(float4*)(Y + (size_t)gr * N + bn + tn + 64) = v1;
        }
    }
}

// ---------------------------------------------------------------- aggregation
// out[v,f] = dinv[v] * ( y[v,f] + sum_{u in in(v)} y[u,f] ) + bias[f]   (+optional relu)
template<int F, bool RELU>
__global__ __launch_bounds__(F) void aggregate_kernel(
    const float* __restrict__ Y, const int* __restrict__ csr_src,
    const unsigned* __restrict__ off, const float* __restrict__ dinv,
    const float* __restrict__ bias, float* __restrict__ out)
{
    const int v = blockIdx.x;
    const int f = threadIdx.x;
    const unsigned e0 = off[v], e1 = off[v + 1];
    float acc0 = Y[(size_t)v * F + f];   // self-loop (y already scaled by dinv[src])
    float acc1 = 0.f, acc2 = 0.f, acc3 = 0.f;
    unsigned j = e0;
    for (; j + 4 <= e1; j += 4) {
        int u0 = csr_src[j + 0];
        int u1 = csr_src[j + 1];
        int u2 = csr_src[j + 2];
        int u3 = csr_src[j + 3];
        acc0 += Y[(size_t)u0 * F + f];
        acc1 += Y[(size_t)u1 * F + f];
        acc2 += Y[(size_t)u2 * F + f];
        acc3 += Y[(size_t)u3 * F + f];
    }
    for (; j < e1; ++j) acc0 += Y[(size_t)csr_src[j] * F + f];
    float acc = (acc0 + acc1) + (acc2 + acc3);
    float r = acc * dinv[v] + bias[f];
    if (RELU) r = fmaxf(r, 0.f);
    out[(size_t)v * F + f] = r;
}

// ---------------------------------------------------------------- launch
extern "C" void kernel_launch(void* const* d_in, const int* in_sizes, int n_in,
                              void* d_out, int out_size, void* d_ws, size_t ws_size,
                              hipStream_t stream)
{
    const float* x  = (const float*)d_in[0];      // 50000 x 1100
    const int*   ei = (const int*)d_in[1];        // 2 x 800000 (int32 per harness contract)
    const float* W1 = (const float*)d_in[2];      // 512 x 256
    const float* b1 = (const float*)d_in[3];      // 256
    const float* W2 = (const float*)d_in[4];      // 256 x 128
    const float* b2 = (const float*)d_in[5];      // 128
    float*       out = (float*)d_out;             // 50000 x 128

    const int* e_src = ei;
    const int* e_dst = ei + N_EDGES;

    // workspace carve-up (512B aligned)
    char* ws = (char*)d_ws;
    size_t o = 0;
    auto carve = [&](size_t bytes) -> char* {
        char* p = ws + o;
        o = (o + bytes + 511) & ~(size_t)511;
        return p;
    };
    unsigned* cnt    = (unsigned*)carve((size_t)N_NODES * 4);
    unsigned* cursor = (unsigned*)carve((size_t)N_NODES * 4);
    unsigned* off    = (unsigned*)carve((size_t)(N_NODES + 1) * 4);
    unsigned* bsums  = (unsigned*)carve(64 * 4);
    float*    dinv   = (float*)   carve((size_t)N_NODES * 4);
    int*      csr    = (int*)     carve((size_t)N_EDGES * 4);
    float*    y1     = (float*)   carve((size_t)N_NODES * 256 * 4);  // reused as y2
    float*    h      = (float*)   carve((size_t)N_NODES * 256 * 4);
    (void)ws_size;

    hipMemsetAsync(cnt,    0, (size_t)N_NODES * 4, stream);
    hipMemsetAsync(cursor, 0, (size_t)N_NODES * 4, stream);

    const int nScanBlocks = (N_NODES + 1023) / 1024;   // 49

    count_deg_kernel<<<(N_EDGES + 255) / 256, 256, 0, stream>>>(e_dst, cnt, N_EDGES);
    dinv_kernel<<<(N_NODES + 255) / 256, 256, 0, stream>>>(cnt, dinv, N_NODES);
    block_reduce_kernel<<<nScanBlocks, 256, 0, stream>>>(cnt, bsums, N_NODES);
    scan_sums_kernel<<<1, 64, 0, stream>>>(bsums, off, nScanBlocks, N_NODES);
    block_scan_kernel<<<nScanBlocks, 1024, 0, stream>>>(cnt, bsums, off, N_NODES);
    fill_csr_kernel<<<(N_EDGES + 255) / 256, 256, 0, stream>>>(e_src, e_dst, off, cursor, csr, N_EDGES);

    // layer 1: y1 = dinv * (x[:,588:] @ W1)
    {
        dim3 grid((N_NODES + BM - 1) / BM, 256 / BN);
        gemm_dinv_kernel<<<grid, 256, 0, stream>>>(x + 588, 1100, W1, dinv, y1,
                                                   N_NODES, 512, 256);
    }
    // h = relu(dinv * rowsum(y1) + b1)
    aggregate_kernel<256, true><<<N_NODES, 256, 0, stream>>>(y1, csr, off, dinv, b1, h);

    // layer 2: y2 = dinv * (h @ W2)   (reuse y1 buffer)
    {
        dim3 grid((N_NODES + BM - 1) / BM, 128 / BN);
        gemm_dinv_kernel<<<grid, 256, 0, stream>>>(h, 256, W2, dinv, y1,
                                                   N_NODES, 256, 128);
    }
    // out = dinv * rowsum(y2) + b2
    aggregate_kernel<128, false><<<N_NODES, 128, 0, stream>>>(y1, csr, off, dinv, b2, out);
}

// Round 4
// 659.464 us; speedup vs baseline: 1.3701x; 1.1533x over previous
//
#include <hip/hip_runtime.h>
#include <hip/hip_bf16.h>
#include <stdint.h>

#define N_NODES 50000
#define N_EDGES 800000

typedef __attribute__((ext_vector_type(8))) __bf16 bf16x8;
typedef __attribute__((ext_vector_type(4))) float floatx4;

// ---------------------------------------------------------------- bf16 split helpers
__device__ __forceinline__ unsigned short f2bf(float f) {
    union { float f; unsigned u; } v; v.f = f;
    unsigned r = v.u + 0x7fffu + ((v.u >> 16) & 1u);   // RNE
    return (unsigned short)(r >> 16);
}
__device__ __forceinline__ float bf2f(unsigned short h) {
    union { unsigned u; float f; } v; v.u = ((unsigned)h) << 16;
    return v.f;
}

// ---------------------------------------------------------------- degree count
__global__ __launch_bounds__(256) void count_deg_kernel(
    const int* __restrict__ dst, unsigned* __restrict__ cnt, int nE)
{
    int i = blockIdx.x * blockDim.x + threadIdx.x;
    if (i < nE) {
        unsigned d = (unsigned)dst[i];
        if (d < N_NODES) atomicAdd(&cnt[d], 1u);
    }
}

// ---------------------------------------------------------------- dinv = rsqrt(deg+1)
__global__ __launch_bounds__(256) void dinv_kernel(
    const unsigned* __restrict__ cnt, float* __restrict__ dinv, int n)
{
    int i = blockIdx.x * blockDim.x + threadIdx.x;
    if (i < n) dinv[i] = rsqrtf((float)(cnt[i] + 1u));
}

// ---------------------------------------------------------------- hierarchical scan
__global__ __launch_bounds__(256) void block_reduce_kernel(
    const unsigned* __restrict__ cnt, unsigned* __restrict__ blockSums, int n)
{
    __shared__ unsigned s[256];
    int b = blockIdx.x;
    int base = b * 1024;
    unsigned v = 0;
    for (int i = threadIdx.x; i < 1024; i += 256) {
        int idx = base + i;
        v += (idx < n) ? cnt[idx] : 0u;
    }
    s[threadIdx.x] = v; __syncthreads();
    for (int st = 128; st > 0; st >>= 1) {
        if (threadIdx.x < st) s[threadIdx.x] += s[threadIdx.x + st];
        __syncthreads();
    }
    if (threadIdx.x == 0) blockSums[b] = s[0];
}

__global__ __launch_bounds__(64) void scan_sums_kernel(
    unsigned* __restrict__ blockSums, unsigned* __restrict__ off, int nb, int n)
{
    __shared__ unsigned s[64];
    int t = threadIdx.x;
    unsigned v = (t < nb) ? blockSums[t] : 0u;
    s[t] = v; __syncthreads();
    for (int st = 1; st < 64; st <<= 1) {
        unsigned add = (t >= st) ? s[t - st] : 0u;
        __syncthreads();
        s[t] += add;
        __syncthreads();
    }
    if (t < nb) blockSums[t] = s[t] - v;   // exclusive
    if (t == 0) off[n] = s[63];            // grand total
}

__global__ __launch_bounds__(1024) void block_scan_kernel(
    const unsigned* __restrict__ cnt, const unsigned* __restrict__ blockSums,
    unsigned* __restrict__ off, int n)
{
    __shared__ unsigned s[1024];
    int b = blockIdx.x, t = threadIdx.x;
    int i = b * 1024 + t;
    unsigned v = (i < n) ? cnt[i] : 0u;
    s[t] = v; __syncthreads();
    for (int st = 1; st < 1024; st <<= 1) {
        unsigned add = (t >= st) ? s[t - st] : 0u;
        __syncthreads();
        s[t] += add;
        __syncthreads();
    }
    if (i < n) off[i] = blockSums[b] + s[t] - v;
}

// ---------------------------------------------------------------- CSR fill
__global__ __launch_bounds__(256) void fill_csr_kernel(
    const int* __restrict__ src, const int* __restrict__ dst,
    const unsigned* __restrict__ off, unsigned* __restrict__ cursor,
    int* __restrict__ csr_src, int nE)
{
    int i = blockIdx.x * blockDim.x + threadIdx.x;
    if (i < nE) {
        unsigned d = (unsigned)dst[i];
        unsigned s = (unsigned)src[i];
        if (d < N_NODES && s < N_NODES) {
            unsigned slot = off[d] + atomicAdd(&cursor[d], 1u);
            csr_src[slot] = (int)s;
        }
    }
}

// ---------------------------------------------------------------- W pre-split + transpose
// W: K x N row-major fp32  ->  WTh/WTl: N x K bf16 (hi/lo), k-contiguous
__global__ __launch_bounds__(256) void split_w_kernel(
    const float* __restrict__ W, unsigned short* __restrict__ Th,
    unsigned short* __restrict__ Tl, int K, int N)
{
    int i = blockIdx.x * blockDim.x + threadIdx.x;
    if (i < K * N) {
        int k = i / N;
        int n = i - k * N;
        float w = W[i];
        unsigned short hi = f2bf(w);
        unsigned short lo = f2bf(w - bf2f(hi));
        Th[(size_t)n * K + k] = hi;
        Tl[(size_t)n * K + k] = lo;
    }
}

// ---------------------------------------------------------------- MFMA split-bf16 GEMM
// Y[m,n] = dinv[m] * sum_k A[m,k] * W[k,n]
// A either fp32 (Afp, stride lda) or pre-split bf16 pair (Ah/Al, pitch apitch).
// B given as pre-split transposed bf16: BT[n*K + k].
// Tile 128x128, BK=32, 4 waves in 2x2, each wave 64x64 via 4x4 16x16x32 MFMAs.
// 3 passes: hi*hi + lo*hi + hi*lo  (fp32-equivalent accuracy).
#define GBM 128
#define GBN 128
#define GBK 32

// swizzled LDS chunk offset (elements). Row stride 32 ushorts = 64B; the
// quad-chunk xor breaks the 8-bank aliasing of the 64B stride (2-way max).
__device__ __forceinline__ int chunk_off(int row, int q) {
    return row * 32 + ((q ^ ((row >> 1) & 3)) << 3);
}

template<bool AFP32>
__global__ __launch_bounds__(256) void gemm_mfma_kernel(
    const float* __restrict__ Afp, int lda,
    const unsigned short* __restrict__ Ah, const unsigned short* __restrict__ Al, int apitch,
    const unsigned short* __restrict__ BTh, const unsigned short* __restrict__ BTl,
    const float* __restrict__ dinv, float* __restrict__ Y,
    int M, int K, int N)
{
    __shared__ unsigned short sAh[GBM * GBK];
    __shared__ unsigned short sAl[GBM * GBK];
    __shared__ unsigned short sBh[GBN * GBK];
    __shared__ unsigned short sBl[GBN * GBK];

    const int t    = threadIdx.x;
    const int bm   = blockIdx.x * GBM;
    const int bn   = blockIdx.y * GBN;
    const int w    = t >> 6;
    const int lane = t & 63;
    const int wx   = w & 1;
    const int wy   = w >> 1;
    const int ml   = lane & 15;
    const int quad = lane >> 4;

    // staging role: 2 threads per tile row, each covers 16 k (2 chunks of 8)
    const int sr = t >> 1;
    const int q0 = (t & 1) * 2;     // first chunk id (0 or 2)

    floatx4 zero4 = {0.f, 0.f, 0.f, 0.f};
    floatx4 acc[4][4];
    #pragma unroll
    for (int i = 0; i < 4; ++i)
        #pragma unroll
        for (int j = 0; j < 4; ++j) acc[i][j] = zero4;

    for (int k0 = 0; k0 < K; k0 += GBK) {
        // ---- stage A
        if (AFP32) {
            int gr = bm + sr;
            #pragma unroll
            for (int c = 0; c < 2; ++c) {
                int q = q0 + c;
                float4 v0, v1;
                if (gr < M) {
                    const float* ap = Afp + (size_t)gr * lda + k0 + q * 8;
                    v0 = *(const float4*)(ap);
                    v1 = *(const float4*)(ap + 4);
                } else {
                    v0 = make_float4(0.f,0.f,0.f,0.f);
                    v1 = make_float4(0.f,0.f,0.f,0.f);
                }
                union { unsigned short us[8]; uint4 v; } ph, pl;
                float f[8] = {v0.x, v0.y, v0.z, v0.w, v1.x, v1.y, v1.z, v1.w};
                #pragma unroll
                for (int e = 0; e < 8; ++e) {
                    unsigned short hi = f2bf(f[e]);
                    ph.us[e] = hi;
                    pl.us[e] = f2bf(f[e] - bf2f(hi));
                }
                int off = chunk_off(sr, q);
                *(uint4*)&sAh[off] = ph.v;
                *(uint4*)&sAl[off] = pl.v;
            }
        } else {
            int gr = bm + sr;
            #pragma unroll
            for (int c = 0; c < 2; ++c) {
                int q = q0 + c;
                uint4 vh, vl;
                if (gr < M) {
                    vh = *(const uint4*)(Ah + (size_t)gr * apitch + k0 + q * 8);
                    vl = *(const uint4*)(Al + (size_t)gr * apitch + k0 + q * 8);
                } else {
                    vh = make_uint4(0,0,0,0);
                    vl = make_uint4(0,0,0,0);
                }
                int off = chunk_off(sr, q);
                *(uint4*)&sAh[off] = vh;
                *(uint4*)&sAl[off] = vl;
            }
        }
        // ---- stage B (always bf16 pair, n-major pitch K)
        {
            int nr = sr;                       // 0..127 within tile
            const unsigned short* bh = BTh + (size_t)(bn + nr) * K + k0;
            const unsigned short* bl = BTl + (size_t)(bn + nr) * K + k0;
            #pragma unroll
            for (int c = 0; c < 2; ++c) {
                int q = q0 + c;
                uint4 vh = *(const uint4*)(bh + q * 8);
                uint4 vl = *(const uint4*)(bl + q * 8);
                int off = chunk_off(nr, q);
                *(uint4*)&sBh[off] = vh;
                *(uint4*)&sBl[off] = vl;
            }
        }
        __syncthreads();

        // ---- fragments
        bf16x8 fAh[4], fAl[4], fBh[4], fBl[4];
        #pragma unroll
        for (int i = 0; i < 4; ++i) {
            int row = wy * 64 + i * 16 + ml;
            int off = chunk_off(row, quad);
            fAh[i] = *(const bf16x8*)&sAh[off];
            fAl[i] = *(const bf16x8*)&sAl[off];
        }
        #pragma unroll
        for (int j = 0; j < 4; ++j) {
            int nrow = wx * 64 + j * 16 + ml;
            int off = chunk_off(nrow, quad);
            fBh[j] = *(const bf16x8*)&sBh[off];
            fBl[j] = *(const bf16x8*)&sBl[off];
        }

        // ---- 3-pass MFMA
        #pragma unroll
        for (int i = 0; i < 4; ++i)
            #pragma unroll
            for (int j = 0; j < 4; ++j) {
                floatx4 c = acc[i][j];
                c = __builtin_amdgcn_mfma_f32_16x16x32_bf16(fAh[i], fBh[j], c, 0, 0, 0);
                c = __builtin_amdgcn_mfma_f32_16x16x32_bf16(fAl[i], fBh[j], c, 0, 0, 0);
                c = __builtin_amdgcn_mfma_f32_16x16x32_bf16(fAh[i], fBl[j], c, 0, 0, 0);
                acc[i][j] = c;
            }
        __syncthreads();
    }

    // ---- epilogue: row = quad*4 + reg, col = ml
    #pragma unroll
    for (int i = 0; i < 4; ++i) {
        int rb = bm + wy * 64 + i * 16 + quad * 4;
        float sc[4];
        #pragma unroll
        for (int r = 0; r < 4; ++r) sc[r] = (rb + r < M) ? dinv[rb + r] : 0.f;
        #pragma unroll
        for (int j = 0; j < 4; ++j) {
            int col = bn + wx * 64 + j * 16 + ml;
            #pragma unroll
            for (int r = 0; r < 4; ++r) {
                int grow = rb + r;
                if (grow < M) Y[(size_t)grow * N + col] = acc[i][j][r] * sc[r];
            }
        }
    }
}

// ---------------------------------------------------------------- aggregation, F=256 -> bf16 hi/lo h
// 4 nodes per 256-block, 64 lanes per node, float4 per lane.
__global__ __launch_bounds__(256) void aggregate256_kernel(
    const float* __restrict__ Y, const int* __restrict__ csr_src,
    const unsigned* __restrict__ off, const float* __restrict__ dinv,
    const float* __restrict__ bias,
    unsigned short* __restrict__ Hh, unsigned short* __restrict__ Hl)
{
    const int v  = blockIdx.x * 4 + (threadIdx.x >> 6);
    const int f0 = (threadIdx.x & 63) * 4;

    float4 a0 = *(const float4*)(Y + (size_t)v * 256 + f0);   // self loop
    float4 a1 = make_float4(0.f,0.f,0.f,0.f);
    float4 a2 = make_float4(0.f,0.f,0.f,0.f);
    float4 a3 = make_float4(0.f,0.f,0.f,0.f);

    const unsigned e0 = off[v], e1 = off[v + 1];
    unsigned j = e0;
    for (; j + 4 <= e1; j += 4) {
        int u0 = csr_src[j + 0];
        int u1 = csr_src[j + 1];
        int u2 = csr_src[j + 2];
        int u3 = csr_src[j + 3];
        float4 m0 = *(const float4*)(Y + (size_t)u0 * 256 + f0);
        float4 m1 = *(const float4*)(Y + (size_t)u1 * 256 + f0);
        float4 m2 = *(const float4*)(Y + (size_t)u2 * 256 + f0);
        float4 m3 = *(const float4*)(Y + (size_t)u3 * 256 + f0);
        a0.x += m0.x; a0.y += m0.y; a0.z += m0.z; a0.w += m0.w;
        a1.x += m1.x; a1.y += m1.y; a1.z += m1.z; a1.w += m1.w;
        a2.x += m2.x; a2.y += m2.y; a2.z += m2.z; a2.w += m2.w;
        a3.x += m3.x; a3.y += m3.y; a3.z += m3.z; a3.w += m3.w;
    }
    for (; j < e1; ++j) {
        float4 m = *(const float4*)(Y + (size_t)csr_src[j] * 256 + f0);
        a0.x += m.x; a0.y += m.y; a0.z += m.z; a0.w += m.w;
    }
    float sx = (a0.x + a1.x) + (a2.x + a3.x);
    float sy = (a0.y + a1.y) + (a2.y + a3.y);
    float sz = (a0.z + a1.z) + (a2.z + a3.z);
    float sw = (a0.w + a1.w) + (a2.w + a3.w);

    float dv = dinv[v];
    float4 b = *(const float4*)(bias + f0);
    float r[4];
    r[0] = fmaxf(sx * dv + b.x, 0.f);
    r[1] = fmaxf(sy * dv + b.y, 0.f);
    r[2] = fmaxf(sz * dv + b.z, 0.f);
    r[3] = fmaxf(sw * dv + b.w, 0.f);

    union { unsigned short us[4]; ushort4 v4; } ph, pl;
    #pragma unroll
    for (int e = 0; e < 4; ++e) {
        unsigned short hi = f2bf(r[e]);
        ph.us[e] = hi;
        pl.us[e] = f2bf(r[e] - bf2f(hi));
    }
    *(ushort4*)(Hh + (size_t)v * 256 + f0) = ph.v4;
    *(ushort4*)(Hl + (size_t)v * 256 + f0) = pl.v4;
}

// ---------------------------------------------------------------- aggregation, F=128 -> fp32 out
__global__ __launch_bounds__(256) void aggregate128_kernel(
    const float* __restrict__ Y, const int* __restrict__ csr_src,
    const unsigned* __restrict__ off, const float* __restrict__ dinv,
    const float* __restrict__ bias, float* __restrict__ out)
{
    const int v  = blockIdx.x * 4 + (threadIdx.x >> 6);
    const int f0 = (threadIdx.x & 63) * 2;

    float2 a0 = *(const float2*)(Y + (size_t)v * 128 + f0);   // self loop
    float2 a1 = make_float2(0.f,0.f);
    float2 a2 = make_float2(0.f,0.f);
    float2 a3 = make_float2(0.f,0.f);

    const unsigned e0 = off[v], e1 = off[v + 1];
    unsigned j = e0;
    for (; j + 4 <= e1; j += 4) {
        int u0 = csr_src[j + 0];
        int u1 = csr_src[j + 1];
        int u2 = csr_src[j + 2];
        int u3 = csr_src[j + 3];
        float2 m0 = *(const float2*)(Y + (size_t)u0 * 128 + f0);
        float2 m1 = *(const float2*)(Y + (size_t)u1 * 128 + f0);
        float2 m2 = *(const float2*)(Y + (size_t)u2 * 128 + f0);
        float2 m3 = *(const float2*)(Y + (size_t)u3 * 128 + f0);
        a0.x += m0.x; a0.y += m0.y;
        a1.x += m1.x; a1.y += m1.y;
        a2.x += m2.x; a2.y += m2.y;
        a3.x += m3.x; a3.y += m3.y;
    }
    for (; j < e1; ++j) {
        float2 m = *(const float2*)(Y + (size_t)csr_src[j] * 128 + f0);
        a0.x += m.x; a0.y += m.y;
    }
    float sx = (a0.x + a1.x) + (a2.x + a3.x);
    float sy = (a0.y + a1.y) + (a2.y + a3.y);

    float dv = dinv[v];
    float2 b = *(const float2*)(bias + f0);
    float2 r = make_float2(sx * dv + b.x, sy * dv + b.y);
    *(float2*)(out + (size_t)v * 128 + f0) = r;
}

// ---------------------------------------------------------------- launch
extern "C" void kernel_launch(void* const* d_in, const int* in_sizes, int n_in,
                              void* d_out, int out_size, void* d_ws, size_t ws_size,
                              hipStream_t stream)
{
    const float* x  = (const float*)d_in[0];      // 50000 x 1100
    const int*   ei = (const int*)d_in[1];        // 2 x 800000 (int32)
    const float* W1 = (const float*)d_in[2];      // 512 x 256
    const float* b1 = (const float*)d_in[3];      // 256
    const float* W2 = (const float*)d_in[4];      // 256 x 128
    const float* b2 = (const float*)d_in[5];      // 128
    float*       out = (float*)d_out;             // 50000 x 128

    const int* e_src = ei;
    const int* e_dst = ei + N_EDGES;

    char* ws = (char*)d_ws;
    size_t o = 0;
    auto carve = [&](size_t bytes) -> char* {
        char* p = ws + o;
        o = (o + bytes + 511) & ~(size_t)511;
        return p;
    };
    unsigned*       cnt    = (unsigned*)carve((size_t)N_NODES * 4);
    unsigned*       cursor = (unsigned*)carve((size_t)N_NODES * 4);
    unsigned*       off    = (unsigned*)carve((size_t)(N_NODES + 1) * 4);
    unsigned*       bsums  = (unsigned*)carve(64 * 4);
    float*          dinv   = (float*)carve((size_t)N_NODES * 4);
    int*            csr    = (int*)carve((size_t)N_EDGES * 4);
    unsigned short* WT1h   = (unsigned short*)carve((size_t)512 * 256 * 2);
    unsigned short* WT1l   = (unsigned short*)carve((size_t)512 * 256 * 2);
    unsigned short* WT2h   = (unsigned short*)carve((size_t)256 * 128 * 2);
    unsigned short* WT2l   = (unsigned short*)carve((size_t)256 * 128 * 2);
    float*          y      = (float*)carve((size_t)N_NODES * 256 * 4);   // y1, reused as y2
    unsigned short* Hh     = (unsigned short*)carve((size_t)N_NODES * 256 * 2);
    unsigned short* Hl     = (unsigned short*)carve((size_t)N_NODES * 256 * 2);
    (void)ws_size;

    hipMemsetAsync(cnt,    0, (size_t)N_NODES * 4, stream);
    hipMemsetAsync(cursor, 0, (size_t)N_NODES * 4, stream);

    const int nScanBlocks = (N_NODES + 1023) / 1024;   // 49

    count_deg_kernel<<<(N_EDGES + 255) / 256, 256, 0, stream>>>(e_dst, cnt, N_EDGES);
    dinv_kernel<<<(N_NODES + 255) / 256, 256, 0, stream>>>(cnt, dinv, N_NODES);
    block_reduce_kernel<<<nScanBlocks, 256, 0, stream>>>(cnt, bsums, N_NODES);
    scan_sums_kernel<<<1, 64, 0, stream>>>(bsums, off, nScanBlocks, N_NODES);
    block_scan_kernel<<<nScanBlocks, 1024, 0, stream>>>(cnt, bsums, off, N_NODES);
    fill_csr_kernel<<<(N_EDGES + 255) / 256, 256, 0, stream>>>(e_src, e_dst, off, cursor, csr, N_EDGES);

    split_w_kernel<<<(512 * 256 + 255) / 256, 256, 0, stream>>>(W1, WT1h, WT1l, 512, 256);
    split_w_kernel<<<(256 * 128 + 255) / 256, 256, 0, stream>>>(W2, WT2h, WT2l, 256, 128);

    // layer 1: y = dinv * (x[:,588:] @ W1)   (fp32 A, split on the fly)
    {
        dim3 grid((N_NODES + GBM - 1) / GBM, 256 / GBN);
        gemm_mfma_kernel<true><<<grid, 256, 0, stream>>>(
            x + 588, 1100, nullptr, nullptr, 0, WT1h, WT1l, dinv, y,
            N_NODES, 512, 256);
    }
    // h = relu(dinv * rowsum(y) + b1)  -> bf16 hi/lo
    aggregate256_kernel<<<N_NODES / 4, 256, 0, stream>>>(y, csr, off, dinv, b1, Hh, Hl);

    // layer 2: y = dinv * (h @ W2)   (bf16-pair A)
    {
        dim3 grid((N_NODES + GBM - 1) / GBM, 128 / GBN);
        gemm_mfma_kernel<false><<<grid, 256, 0, stream>>>(
            nullptr, 0, Hh, Hl, 256, WT2h, WT2l, dinv, y,
            N_NODES, 256, 128);
    }
    // out = dinv * rowsum(y) + b2
    aggregate128_kernel<<<N_NODES / 4, 256, 0, stream>>>(y, csr, off, dinv, b2, out);
}